// Round 1
// baseline (372.326 us; speedup 1.0000x reference)
//
#include <hip/hip_runtime.h>

// fc_out[b,o] = concat_gap[b,:]·weight[o,:] + bias[o]           (16x3)
// vis_i[b,0,s] = sum_c out_i[b,c,s] * 0.5*(weight[0,c+off]+weight[1,c+off])
// Output flat f32: fc(48) | vis1(983040) | vis2(131072) | vis3(16384)
//
// All sizes in float4 units:
//   out1: [16][64][15360]   out2: [16][128][2048]   out3: [16][256][256]
// Traffic: 335 MB read + 4.5 MB write -> ~54 us floor @ 6.3 TB/s.
//
// v3: perfect load balance. Every vis block costs exactly 256 KB of reads,
// and the vis grid is exactly 1280 = 5 * 256 CUs (v2 was 641 blocks =
// 2.5/CU -> ~20% tail imbalance on a pure streaming kernel).
//   [0,64)     vis3: 4 blocks/batch, 64-f4 chunk, 4-way channel split + LDS combine
//   [64,320)   vis2: 16 blocks/batch, 128-f4 chunk, 2-way channel split + LDS combine
//   [320,1280) vis1: 60 blocks/batch, 256-f4 chunk, full C=64 per thread
//   1280       fc (tiny, L2-resident, overlaps)

typedef float fvec4 __attribute__((ext_vector_type(4)));

__device__ __forceinline__ fvec4 ntload(const fvec4* p) {
    return __builtin_nontemporal_load(p);
}
__device__ __forceinline__ void ntstore(fvec4* p, fvec4 v) {
    __builtin_nontemporal_store(v, p);
}

__global__ __launch_bounds__(256) void fused_vis_fc_v3(
    const float* __restrict__ concat_gap,
    const float* __restrict__ out1,
    const float* __restrict__ out2,
    const float* __restrict__ out3,
    const float* __restrict__ weight,
    const float* __restrict__ bias,
    float* __restrict__ d_out)
{
    const int t = threadIdx.x;
    int blk = blockIdx.x;

    __shared__ float s_w[256];
    __shared__ fvec4 s_red[192];

    if (blk < 64) {
        // ---- vis3: C=256 in 4 groups of 64, 64-f4 spatial chunk ----
        const int b  = blk >> 2;
        const int s4 = ((blk & 3) << 6) + (t & 63);      // [0,256)
        const int g  = t >> 6;                           // channel group 0..3
        s_w[t] = 0.5f * (weight[192 + t] + weight[640 + t]);
        __syncthreads();

        const fvec4* in4 = (const fvec4*)out3 + (size_t)b * 256 * 256 + s4;
        fvec4 acc = {0.f, 0.f, 0.f, 0.f};
        #pragma unroll 8
        for (int c = 0; c < 64; ++c) {
            const int ch = (g << 6) + c;
            acc += ntload(in4 + (size_t)ch * 256) * s_w[ch];
        }
        if (g) s_red[((g - 1) << 6) + (t & 63)] = acc;
        __syncthreads();
        if (!g) {
            acc += s_red[t] + s_red[64 + t] + s_red[128 + t];
            ntstore((fvec4*)(d_out + 48 + 983040 + 131072) + b * 256 + s4, acc);
        }
    } else if (blk < 320) {
        // ---- vis2: C=128 in 2 halves of 64, 128-f4 spatial chunk ----
        blk -= 64;
        const int b    = blk >> 4;
        const int s4   = ((blk & 15) << 7) + (t & 127);  // [0,2048)
        const int half = t >> 7;                         // 0 or 1
        if (t < 128) s_w[t] = 0.5f * (weight[64 + t] + weight[512 + t]);
        __syncthreads();

        const fvec4* in4 = (const fvec4*)out2 + (size_t)b * 128 * 2048 + s4;
        fvec4 acc = {0.f, 0.f, 0.f, 0.f};
        #pragma unroll 8
        for (int c = 0; c < 64; ++c) {
            const int ch = (half << 6) + c;
            acc += ntload(in4 + (size_t)ch * 2048) * s_w[ch];
        }
        if (half) s_red[t & 127] = acc;
        __syncthreads();
        if (!half) {
            acc += s_red[t];
            ntstore((fvec4*)(d_out + 48 + 983040) + b * 2048 + s4, acc);
        }
    } else if (blk < 1280) {
        // ---- vis1: C=64, S4=15360, 256-f4 chunk, 1 f4/thread ----
        blk -= 320;
        const int b     = blk / 60;
        const int chunk = (blk % 60) << 8;
        if (t < 64) s_w[t] = 0.5f * (weight[t] + weight[448 + t]);
        __syncthreads();

        const fvec4* in4 = (const fvec4*)out1
            + (size_t)b * 64 * 15360 + chunk + t;
        fvec4 acc = {0.f, 0.f, 0.f, 0.f};
        #pragma unroll 8
        for (int c = 0; c < 64; ++c)
            acc += ntload(in4 + (size_t)c * 15360) * s_w[c];
        ntstore((fvec4*)(d_out + 48) + (size_t)b * 15360 + chunk + t, acc);
    } else {
        // ---- fc: 16x3 addmm, L2-resident, overlaps with vis blocks ----
        if (t < 48) {
            const int b = t / 3, o = t % 3;
            const float* g = concat_gap + b * 448;
            const float* w = weight + o * 448;
            float s = 0.f;
            #pragma unroll 8
            for (int k = 0; k < 448; ++k) s += g[k] * w[k];
            d_out[t] = s + bias[o];
        }
    }
}

extern "C" void kernel_launch(void* const* d_in, const int* in_sizes, int n_in,
                              void* d_out, int out_size, void* d_ws, size_t ws_size,
                              hipStream_t stream) {
    fused_vis_fc_v3<<<1281, 256, 0, stream>>>(
        (const float*)d_in[0], (const float*)d_in[1], (const float*)d_in[2],
        (const float*)d_in[3], (const float*)d_in[4], (const float*)d_in[5],
        (float*)d_out);
}